// Round 1
// baseline (244.857 us; speedup 1.0000x reference)
//
#include <hip/hip_runtime.h>
#include <stdint.h>
#include <stddef.h>

#define NEMBD 768
#define NH    12
#define HD    64
#define SEQ   2048
#define TOK   8192
#define QKVN  2304
#define KPAD  88

typedef __attribute__((ext_vector_type(4))) float f32x4;
typedef __attribute__((ext_vector_type(8))) __bf16 bf8;
typedef __attribute__((ext_vector_type(8))) short s16x8;
typedef __attribute__((ext_vector_type(4))) short s16x4;

static __device__ __forceinline__ short f2bf(float f) {
  union { float f; unsigned u; } v; v.f = f;
  unsigned u = v.u;
  u += 0x7fffu + ((u >> 16) & 1u);   // round-to-nearest-even
  return (short)(u >> 16);
}

typedef const __attribute__((address_space(1))) unsigned int* gp1;
typedef __attribute__((address_space(3))) unsigned int* lp3;
static __device__ __forceinline__ void gload_lds16(const void* g, void* l) {
  __builtin_amdgcn_global_load_lds((gp1)g, (lp3)l, 16, 0, 0);
}

// ---------------- prep: fp32 -> bf16 conversions ----------------
__global__ __launch_bounds__(256) void prep_x_kern(const float* __restrict__ x,
                                                   short* __restrict__ xb) {
  int i = (blockIdx.x * 256 + threadIdx.x) * 4;
  f32x4 v = *(const f32x4*)(x + i);
  s16x4 o;
#pragma unroll
  for (int j = 0; j < 4; ++j) o[j] = f2bf(v[j]);
  *(s16x4*)(xb + i) = o;
}

__global__ __launch_bounds__(256) void prep_w_kern(
    const float* __restrict__ wq, const float* __restrict__ wk, const float* __restrict__ wv,
    const float* __restrict__ wo, const float* __restrict__ bq, const float* __restrict__ bk,
    const float* __restrict__ bv, short* __restrict__ wqkv, short* __restrict__ wo16,
    float* __restrict__ bqkv) {
  const int WN = NEMBD * NEMBD;      // 589824
  int t = blockIdx.x * 256 + threadIdx.x;
  const int n4 = WN;                 // (3*WN + WN)/4
  if (t < n4) {
    int i4 = t * 4;
    const float* src; short* dst; int rem;
    if (i4 < 3 * WN) {
      int which = i4 / WN;
      rem = i4 - which * WN;
      src = which == 0 ? wq : (which == 1 ? wk : wv);
      dst = wqkv + i4;
    } else {
      rem = i4 - 3 * WN;
      src = wo;
      dst = wo16 + rem;
    }
    f32x4 v = *(const f32x4*)(src + rem);
    s16x4 o;
#pragma unroll
    for (int j = 0; j < 4; ++j) o[j] = f2bf(v[j]);
    *(s16x4*)dst = o;
  } else {
    int t2 = t - n4;
    if (t2 < QKVN) {
      int which = t2 / NEMBD, rem = t2 - which * NEMBD;
      bqkv[t2] = (which == 0 ? bq : (which == 1 ? bk : bv))[rem];
    }
  }
}

// ---------------- GEMM: C[m][n] = sum_k A[m][k]*B[n][k] + bias[n] ----------------
// MODE 0: scatter bf16 into Q/K/V [b,h,s,d].  MODE 1: fp32 out [M][N].
template <int MODE>
__global__ __launch_bounds__(256) void gemm128(
    const short* __restrict__ A, const short* __restrict__ Bw, const float* __restrict__ bias,
    short* __restrict__ q_out, short* __restrict__ k_out, short* __restrict__ v_out,
    float* __restrict__ c_out, int M, int N, int K) {
  __shared__ short As[128 * 64];
  __shared__ short Bs[128 * 64];
  const int tid = threadIdx.x;
  const int wave = tid >> 6, lane = tid & 63;
  const int r = lane & 15, g = lane >> 4;
  const int n0 = blockIdx.x * 128, m0 = blockIdx.y * 128;
  const int wm0 = (wave >> 1) * 64, wn0 = (wave & 1) * 64;
  const int lrow = lane >> 3, lcol = (lane & 7) * 8;

  f32x4 acc[4][4];
#pragma unroll
  for (int mi = 0; mi < 4; ++mi)
#pragma unroll
    for (int ni = 0; ni < 4; ++ni) acc[mi][ni] = (f32x4){0.f, 0.f, 0.f, 0.f};

  for (int kt = 0; kt < K; kt += 64) {
#pragma unroll
    for (int ii = 0; ii < 4; ++ii) {
      int blk = wave * 4 + ii;                       // 16 chunks of 8 rows
      gload_lds16(A + (size_t)(m0 + blk * 8 + lrow) * K + kt + lcol, &As[blk * 512]);
      gload_lds16(Bw + (size_t)(n0 + blk * 8 + lrow) * K + kt + lcol, &Bs[blk * 512]);
    }
    __syncthreads();
#pragma unroll
    for (int kk = 0; kk < 2; ++kk) {
      bf8 af[4], bfv[4];
#pragma unroll
      for (int mi = 0; mi < 4; ++mi)
        af[mi] = *(const bf8*)&As[(wm0 + 16 * mi + r) * 64 + kk * 32 + g * 8];
#pragma unroll
      for (int ni = 0; ni < 4; ++ni)
        bfv[ni] = *(const bf8*)&Bs[(wn0 + 16 * ni + r) * 64 + kk * 32 + g * 8];
#pragma unroll
      for (int mi = 0; mi < 4; ++mi)
#pragma unroll
        for (int ni = 0; ni < 4; ++ni)
          acc[mi][ni] = __builtin_amdgcn_mfma_f32_16x16x32_bf16(af[mi], bfv[ni], acc[mi][ni], 0, 0, 0);
    }
    __syncthreads();
  }

#pragma unroll
  for (int ni = 0; ni < 4; ++ni) {
    int col = n0 + wn0 + 16 * ni + r;
    float bcol = bias[col];
    if (MODE == 0) {
      int which = col / NEMBD;
      int rem = col - which * NEMBD;
      int h = rem >> 6, d = rem & 63;
      short* dst = which == 0 ? q_out : (which == 1 ? k_out : v_out);
#pragma unroll
      for (int mi = 0; mi < 4; ++mi)
#pragma unroll
        for (int j = 0; j < 4; ++j) {
          int row = m0 + wm0 + 16 * mi + 4 * g + j;
          int b = row >> 11, s = row & 2047;
          dst[(((size_t)(b * NH + h)) * SEQ + s) * HD + d] = f2bf(acc[mi][ni][j] + bcol);
        }
    } else {
#pragma unroll
      for (int mi = 0; mi < 4; ++mi)
#pragma unroll
        for (int j = 0; j < 4; ++j) {
          int row = m0 + wm0 + 16 * mi + 4 * g + j;
          c_out[(size_t)row * N + col] = acc[mi][ni][j] + bcol;
        }
    }
  }
}

// ---------------- flash attention ----------------
// Per block: one (b,h), 64 q-rows; 4 waves x 16 rows. KV tiles of 64.
// QK^T computed swapped: mfma(K, Q) -> lane holds q-row (lane&15), kv-cols lane-local.
__global__ __launch_bounds__(256) void attn_kern(
    const short* __restrict__ Qg, const short* __restrict__ Kg, const short* __restrict__ Vg,
    short* __restrict__ Ao) {
  __shared__ short Kl[64 * KPAD];        // [c][d], padded rows (176B, 16B-aligned)
  __shared__ short Vt[64 * 64];          // [d][c], XOR-swizzled c
  __shared__ short Pl[4][16 * KPAD];     // per-wave P[r][c]

  const int tid = threadIdx.x;
  const int wave = tid >> 6, lane = tid & 63;
  const int r = lane & 15, g = lane >> 4;
  const int bh = blockIdx.y;
  const int q0 = blockIdx.x * 64;
  const size_t base = (size_t)bh * SEQ * HD;

  bf8 qf[2];
#pragma unroll
  for (int kk = 0; kk < 2; ++kk)
    qf[kk] = *(const bf8*)&Qg[base + (size_t)(q0 + wave * 16 + r) * HD + kk * 32 + g * 8];

  float m_run = -__builtin_inff(), lsum = 0.f;
  f32x4 o[4];
#pragma unroll
  for (int fd = 0; fd < 4; ++fd) o[fd] = (f32x4){0.f, 0.f, 0.f, 0.f};

  const int sc = lane & 7;
  const int crw = wave * 8 + (lane >> 3);

  for (int t = 0; t < SEQ / 64; ++t) {
    // stage K tile [64][64] (padded) and V tile transposed+swizzled
#pragma unroll
    for (int p = 0; p < 2; ++p) {
      int c = crw + p * 32;
      const size_t gsrc = base + (size_t)(t * 64 + c) * HD + sc * 8;
      s16x8 kv = *(const s16x8*)&Kg[gsrc];
      *(s16x8*)&Kl[c * KPAD + sc * 8] = kv;
      s16x8 vv = *(const s16x8*)&Vg[gsrc];
#pragma unroll
      for (int jj = 0; jj < 8; ++jj)
        Vt[(sc * 8 + jj) * 64 + (c ^ (sc * 8))] = vv[jj];
    }
    __syncthreads();

    // S^T = K * Q^T : lane holds q-row r, kv-cols c = 16f + 4g + j
    f32x4 sv[4];
#pragma unroll
    for (int f = 0; f < 4; ++f) sv[f] = (f32x4){0.f, 0.f, 0.f, 0.f};
#pragma unroll
    for (int kk = 0; kk < 2; ++kk)
#pragma unroll
      for (int f = 0; f < 4; ++f) {
        bf8 kf = *(const bf8*)&Kl[(16 * f + r) * KPAD + kk * 32 + g * 8];
        sv[f] = __builtin_amdgcn_mfma_f32_16x16x32_bf16(kf, qf[kk], sv[f], 0, 0, 0);
      }

    // online softmax (row r spread over lanes r, r+16, r+32, r+48)
    float tmax = -__builtin_inff();
#pragma unroll
    for (int f = 0; f < 4; ++f)
#pragma unroll
      for (int j = 0; j < 4; ++j) { sv[f][j] *= 0.125f; tmax = fmaxf(tmax, sv[f][j]); }
    tmax = fmaxf(tmax, __shfl_xor(tmax, 16));
    tmax = fmaxf(tmax, __shfl_xor(tmax, 32));
    float m_new = fmaxf(m_run, tmax);
    float corr = __expf(m_run - m_new);
    float tsum = 0.f;
#pragma unroll
    for (int f = 0; f < 4; ++f)
#pragma unroll
      for (int j = 0; j < 4; ++j) {
        float pv = __expf(sv[f][j] - m_new);
        sv[f][j] = pv;
        tsum += pv;
      }
    tsum += __shfl_xor(tsum, 16);
    tsum += __shfl_xor(tsum, 32);
    lsum = lsum * corr + tsum;
    m_run = m_new;

    // P -> per-wave LDS (bf16), layout [r][c]
#pragma unroll
    for (int f = 0; f < 4; ++f) {
      s16x4 pk;
#pragma unroll
      for (int j = 0; j < 4; ++j) pk[j] = f2bf(sv[f][j]);
      *(s16x4*)&Pl[wave][r * KPAD + 16 * f + 4 * g] = pk;
    }

    // rescale O (O rows live at 4g+j; stats live keyed by lane&15)
#pragma unroll
    for (int j = 0; j < 4; ++j) {
      float cj = __shfl(corr, 4 * g + j);
#pragma unroll
      for (int fd = 0; fd < 4; ++fd) o[fd][j] *= cj;
    }

    // O += P * V
#pragma unroll
    for (int kk = 0; kk < 2; ++kk) {
      bf8 pa = *(const bf8*)&Pl[wave][r * KPAD + kk * 32 + g * 8];
#pragma unroll
      for (int fd = 0; fd < 4; ++fd) {
        int d = 16 * fd + r;
        int swz = ((d >> 3) & 7) * 8;
        bf8 vb = *(const bf8*)&Vt[d * 64 + ((kk * 32 + g * 8) ^ swz)];
        o[fd] = __builtin_amdgcn_mfma_f32_16x16x32_bf16(pa, vb, o[fd], 0, 0, 0);
      }
    }
    __syncthreads();
  }

  float inv = 1.f / lsum;
  const int b = bh / NH, h = bh - b * NH;
#pragma unroll
  for (int j = 0; j < 4; ++j) {
    float ij = __shfl(inv, 4 * g + j);
    int srow_o = q0 + wave * 16 + 4 * g + j;
    size_t obase = ((size_t)(b * SEQ + srow_o)) * NEMBD + h * HD;
#pragma unroll
    for (int fd = 0; fd < 4; ++fd)
      Ao[obase + 16 * fd + r] = f2bf(o[fd][j] * ij);
  }
}

// ---------------- launcher ----------------
extern "C" void kernel_launch(void* const* d_in, const int* in_sizes, int n_in,
                              void* d_out, int out_size, void* d_ws, size_t ws_size,
                              hipStream_t stream) {
  (void)in_sizes; (void)n_in; (void)out_size; (void)ws_size;
  const float* x   = (const float*)d_in[0];
  const float* wqw = (const float*)d_in[1];
  const float* wqb = (const float*)d_in[2];
  const float* wkw = (const float*)d_in[3];
  const float* wkb = (const float*)d_in[4];
  const float* wvw = (const float*)d_in[5];
  const float* wvb = (const float*)d_in[6];
  const float* wow = (const float*)d_in[7];
  const float* wob = (const float*)d_in[8];

  char* ws = (char*)d_ws;
  short* xb   = (short*)(ws + 0);           // 12,582,912 B (x bf16; later reused as attn out)
  short* wqkv = (short*)(ws + 12582912);    //  3,538,944
  short* wo16 = (short*)(ws + 16121856);    //  1,179,648
  float* bqkv = (float*)(ws + 17301504);    //      9,216
  short* qb   = (short*)(ws + 17310720);    // 12,582,912
  short* kb   = (short*)(ws + 29893632);    // 12,582,912
  short* vb   = (short*)(ws + 42476544);    // 12,582,912 (end 55,059,456)

  prep_x_kern<<<dim3(6144), dim3(256), 0, stream>>>(x, xb);
  prep_w_kern<<<dim3(2313), dim3(256), 0, stream>>>(wqw, wkw, wvw, wow, wqb, wkb, wvb,
                                                    wqkv, wo16, bqkv);
  gemm128<0><<<dim3(QKVN / 128, TOK / 128), dim3(256), 0, stream>>>(
      xb, wqkv, bqkv, qb, kb, vb, nullptr, TOK, QKVN, NEMBD);
  attn_kern<<<dim3(SEQ / 64, 48), dim3(256), 0, stream>>>(qb, kb, vb, xb);
  gemm128<1><<<dim3(NEMBD / 128, TOK / 128), dim3(256), 0, stream>>>(
      xb, wo16, wob, nullptr, nullptr, nullptr, (float*)d_out, TOK, NEMBD, NEMBD);
}

// Round 2
// 202.193 us; speedup vs baseline: 1.2110x; 1.2110x over previous
//
#include <hip/hip_runtime.h>
#include <stdint.h>
#include <stddef.h>

#define NEMBD 768
#define NH    12
#define HD    64
#define SEQ   2048
#define TOK   8192
#define QKVN  2304
#define PSTR  72          // P LDS row stride (shorts)
#define QSCALE 0.18033688011112042f   // log2(e)/8

typedef __attribute__((ext_vector_type(4))) float f32x4;
typedef __attribute__((ext_vector_type(8))) __bf16 bf8;
typedef __attribute__((ext_vector_type(8))) short s16x8;
typedef __attribute__((ext_vector_type(4))) short s16x4;

static __device__ __forceinline__ short f2bf(float f) {
  __bf16 h = (__bf16)f;                 // RNE, compiler packs via v_cvt_pk_bf16_f32
  union { __bf16 h; short s; } u; u.h = h; return u.s;
}

typedef const __attribute__((address_space(1))) unsigned int* gp1;
typedef __attribute__((address_space(3))) unsigned int* lp3;
static __device__ __forceinline__ void gload_lds16(const void* g, void* l) {
  __builtin_amdgcn_global_load_lds((gp1)g, (lp3)l, 16, 0, 0);
}

// ---------------- prep: fp32 -> bf16 conversions ----------------
__global__ __launch_bounds__(256) void prep_x_kern(const float* __restrict__ x,
                                                   short* __restrict__ xb) {
  int i = (blockIdx.x * 256 + threadIdx.x) * 4;
  f32x4 v = *(const f32x4*)(x + i);
  s16x4 o;
#pragma unroll
  for (int j = 0; j < 4; ++j) o[j] = f2bf(v[j]);
  *(s16x4*)(xb + i) = o;
}

__global__ __launch_bounds__(256) void prep_w_kern(
    const float* __restrict__ wq, const float* __restrict__ wk, const float* __restrict__ wv,
    const float* __restrict__ wo, const float* __restrict__ bq, const float* __restrict__ bk,
    const float* __restrict__ bv, short* __restrict__ wqkv, short* __restrict__ wo16,
    float* __restrict__ bqkv) {
  const int WN = NEMBD * NEMBD;      // 589824
  int t = blockIdx.x * 256 + threadIdx.x;
  const int n4 = WN;                 // (3*WN + WN)/4
  if (t < n4) {
    int i4 = t * 4;
    const float* src; short* dst; int rem;
    if (i4 < 3 * WN) {
      int which = i4 / WN;
      rem = i4 - which * WN;
      src = which == 0 ? wq : (which == 1 ? wk : wv);
      dst = wqkv + i4;
    } else {
      rem = i4 - 3 * WN;
      src = wo;
      dst = wo16 + rem;
    }
    f32x4 v = *(const f32x4*)(src + rem);
    s16x4 o;
#pragma unroll
    for (int j = 0; j < 4; ++j) o[j] = f2bf(v[j]);
    *(s16x4*)dst = o;
  } else {
    int t2 = t - n4;
    if (t2 < QKVN) {
      int which = t2 / NEMBD, rem = t2 - which * NEMBD;
      bqkv[t2] = (which == 0 ? bq : (which == 1 ? bk : bv))[rem];
    }
  }
}

// ---------------- GEMM: C[m][n] = sum_k A[m][k]*B[n][k] + bias[n] ----------------
// MODE 0: scatter bf16 into Q (scaled by QSCALE) / K as [b,h,s,d], V as [b,h,d,s].
// MODE 1: fp32 out [M][N].
template <int MODE>
__global__ __launch_bounds__(256) void gemm128(
    const short* __restrict__ A, const short* __restrict__ Bw, const float* __restrict__ bias,
    short* __restrict__ q_out, short* __restrict__ k_out, short* __restrict__ v_out,
    float* __restrict__ c_out, int M, int N, int K) {
  __shared__ short As[128 * 64];
  __shared__ short Bs[128 * 64];
  const int tid = threadIdx.x;
  const int wave = tid >> 6, lane = tid & 63;
  const int r = lane & 15, g = lane >> 4;
  const int n0 = blockIdx.x * 128, m0 = blockIdx.y * 128;
  const int wm0 = (wave >> 1) * 64, wn0 = (wave & 1) * 64;
  const int lrow = lane >> 3, lcol = (lane & 7) * 8;

  f32x4 acc[4][4];
#pragma unroll
  for (int mi = 0; mi < 4; ++mi)
#pragma unroll
    for (int ni = 0; ni < 4; ++ni) acc[mi][ni] = (f32x4){0.f, 0.f, 0.f, 0.f};

  for (int kt = 0; kt < K; kt += 64) {
#pragma unroll
    for (int ii = 0; ii < 4; ++ii) {
      int blk = wave * 4 + ii;                       // 16 chunks of 8 rows
      gload_lds16(A + (size_t)(m0 + blk * 8 + lrow) * K + kt + lcol, &As[blk * 512]);
      gload_lds16(Bw + (size_t)(n0 + blk * 8 + lrow) * K + kt + lcol, &Bs[blk * 512]);
    }
    __syncthreads();
#pragma unroll
    for (int kk = 0; kk < 2; ++kk) {
      bf8 af[4], bfv[4];
#pragma unroll
      for (int mi = 0; mi < 4; ++mi)
        af[mi] = *(const bf8*)&As[(wm0 + 16 * mi + r) * 64 + kk * 32 + g * 8];
#pragma unroll
      for (int ni = 0; ni < 4; ++ni)
        bfv[ni] = *(const bf8*)&Bs[(wn0 + 16 * ni + r) * 64 + kk * 32 + g * 8];
#pragma unroll
      for (int mi = 0; mi < 4; ++mi)
#pragma unroll
        for (int ni = 0; ni < 4; ++ni)
          acc[mi][ni] = __builtin_amdgcn_mfma_f32_16x16x32_bf16(af[mi], bfv[ni], acc[mi][ni], 0, 0, 0);
    }
    __syncthreads();
  }

#pragma unroll
  for (int ni = 0; ni < 4; ++ni) {
    int col = n0 + wn0 + 16 * ni + r;
    float bcol = bias[col];
    if (MODE == 0) {
      int which = col / NEMBD;
      int rem = col - which * NEMBD;
      int h = rem >> 6, d = rem & 63;
      if (which == 2) {
        // V stored transposed: [b,h,d,s]; pack 4 consecutive s per lane
#pragma unroll
        for (int mi = 0; mi < 4; ++mi) {
          int s0 = m0 + wm0 + 16 * mi + 4 * g;
          int b = s0 >> 11, s = s0 & 2047;
          s16x4 pk;
#pragma unroll
          for (int j = 0; j < 4; ++j) pk[j] = f2bf(acc[mi][ni][j] + bcol);
          *(s16x4*)&v_out[(((size_t)(b * NH + h)) * HD + d) * SEQ + s] = pk;
        }
      } else {
        short* dst = which == 0 ? q_out : k_out;
        float sc = which == 0 ? QSCALE : 1.0f;
#pragma unroll
        for (int mi = 0; mi < 4; ++mi)
#pragma unroll
          for (int j = 0; j < 4; ++j) {
            int row = m0 + wm0 + 16 * mi + 4 * g + j;
            int b = row >> 11, s = row & 2047;
            dst[(((size_t)(b * NH + h)) * SEQ + s) * HD + d] = f2bf((acc[mi][ni][j] + bcol) * sc);
          }
      }
    } else {
#pragma unroll
      for (int mi = 0; mi < 4; ++mi)
#pragma unroll
        for (int j = 0; j < 4; ++j) {
          int row = m0 + wm0 + 16 * mi + 4 * g + j;
          c_out[(size_t)row * N + col] = acc[mi][ni][j] + bcol;
        }
    }
  }
}

// ---------------- flash attention ----------------
// Per block: one (b,h), 64 q-rows; 4 waves x 16 rows. KV tiles of 64.
// QK^T swapped: mfma(K, Q) -> lane holds q-row (lane&15); softmax in base-2
// (Q pre-scaled by log2(e)/8 in the QKV GEMM epilogue).
// K staged [c][d], V staged [d][c] (from global V^T) -- both via global_load_lds
// with XOR-swizzled source chunks; reads XOR byte ^= (row&7)<<4.
__global__ __launch_bounds__(256) void attn_kern(
    const short* __restrict__ Qg, const short* __restrict__ Kg, const short* __restrict__ Vtg,
    short* __restrict__ Ao) {
  __shared__ short Kl[64 * 64];          // swizzled [c][d]
  __shared__ short Vl[64 * 64];          // swizzled [d][c]
  __shared__ short Pl[4][16 * PSTR];     // per-wave P[r][c]

  const int tid = threadIdx.x;
  const int wave = tid >> 6, lane = tid & 63;
  const int r = lane & 15, g = lane >> 4;
  const int bh = blockIdx.y;
  const int q0 = blockIdx.x * 64;
  const size_t base = (size_t)bh * (SEQ * HD);   // same offset for [s][d] and [d][s]

  bf8 qf[2];
#pragma unroll
  for (int kk = 0; kk < 2; ++kk)
    qf[kk] = *(const bf8*)&Qg[base + (size_t)(q0 + wave * 16 + r) * HD + kk * 32 + g * 8];

  float m_run = -__builtin_inff(), lsum = 0.f;
  f32x4 o[4];
#pragma unroll
  for (int fd = 0; fd < 4; ++fd) o[fd] = (f32x4){0.f, 0.f, 0.f, 0.f};

  const int cbr = (r & 7) << 4;          // read-side XOR (bytes)

  for (int t = 0; t < SEQ / 64; ++t) {
    // stage K [64 s][64 d] and V^T [64 d][64 s], linear LDS + pre-swizzled source
#pragma unroll
    for (int p = 0; p < 2; ++p) {
      int i = p * 256 + tid;
      int row = i >> 3;
      int c8 = ((i & 7) ^ (row & 7)) * 8;          // source chunk (shorts)
      gload_lds16(Kg + base + (size_t)(t * 64 + row) * HD + c8, &Kl[p * 2048 + wave * 512]);
      gload_lds16(Vtg + base + (size_t)row * SEQ + t * 64 + c8, &Vl[p * 2048 + wave * 512]);
    }
    __syncthreads();

    // S^T = K * Q^T : lane holds q-row r, kv-cols 16f+4g+j
    f32x4 sv[4];
#pragma unroll
    for (int f = 0; f < 4; ++f) sv[f] = (f32x4){0.f, 0.f, 0.f, 0.f};
#pragma unroll
    for (int kk = 0; kk < 2; ++kk) {
      int cb = (kk * 64 + g * 16) ^ cbr;
#pragma unroll
      for (int f = 0; f < 4; ++f) {
        bf8 kf = *(const bf8*)((const char*)Kl + (16 * f + r) * 128 + cb);
        sv[f] = __builtin_amdgcn_mfma_f32_16x16x32_bf16(kf, qf[kk], sv[f], 0, 0, 0);
      }
    }

    // online softmax, base-2 (S already scaled by log2e/8 via Q)
    float tmax = -__builtin_inff();
#pragma unroll
    for (int f = 0; f < 4; ++f)
#pragma unroll
      for (int j = 0; j < 4; ++j) tmax = fmaxf(tmax, sv[f][j]);
    tmax = fmaxf(tmax, __shfl_xor(tmax, 16));
    tmax = fmaxf(tmax, __shfl_xor(tmax, 32));
    float m_new = fmaxf(m_run, tmax);
    float corr = __builtin_amdgcn_exp2f(m_run - m_new);
    float tsum = 0.f;
#pragma unroll
    for (int f = 0; f < 4; ++f)
#pragma unroll
      for (int j = 0; j < 4; ++j) {
        float pv = __builtin_amdgcn_exp2f(sv[f][j] - m_new);
        sv[f][j] = pv;
        tsum += pv;
      }
    tsum += __shfl_xor(tsum, 16);
    tsum += __shfl_xor(tsum, 32);
    lsum = lsum * corr + tsum;

    // P -> per-wave LDS (bf16), layout [r][c]
#pragma unroll
    for (int f = 0; f < 4; ++f) {
      s16x4 pk;
#pragma unroll
      for (int j = 0; j < 4; ++j) pk[j] = f2bf(sv[f][j]);
      *(s16x4*)&Pl[wave][r * PSTR + 16 * f + 4 * g] = pk;
    }

    // rescale O only when some row's max moved (O rows live at 4g+j)
    if (!__all(m_new == m_run)) {
#pragma unroll
      for (int j = 0; j < 4; ++j) {
        float cj = __shfl(corr, 4 * g + j);
#pragma unroll
        for (int fd = 0; fd < 4; ++fd) o[fd][j] *= cj;
      }
    }
    m_run = m_new;

    // O += P * V
#pragma unroll
    for (int kk = 0; kk < 2; ++kk) {
      bf8 pa = *(const bf8*)&Pl[wave][r * PSTR + kk * 32 + g * 8];
      int cb = (kk * 64 + g * 16) ^ cbr;
#pragma unroll
      for (int fd = 0; fd < 4; ++fd) {
        bf8 vb = *(const bf8*)((const char*)Vl + (16 * fd + r) * 128 + cb);
        o[fd] = __builtin_amdgcn_mfma_f32_16x16x32_bf16(pa, vb, o[fd], 0, 0, 0);
      }
    }
    __syncthreads();
  }

  float inv = 1.f / lsum;
  const int b = bh / NH, h = bh - b * NH;
#pragma unroll
  for (int j = 0; j < 4; ++j) {
    float ij = __shfl(inv, 4 * g + j);
    int srow_o = q0 + wave * 16 + 4 * g + j;
    size_t obase = ((size_t)(b * SEQ + srow_o)) * NEMBD + h * HD;
#pragma unroll
    for (int fd = 0; fd < 4; ++fd)
      Ao[obase + 16 * fd + r] = f2bf(o[fd][j] * ij);
  }
}

// ---------------- launcher ----------------
extern "C" void kernel_launch(void* const* d_in, const int* in_sizes, int n_in,
                              void* d_out, int out_size, void* d_ws, size_t ws_size,
                              hipStream_t stream) {
  (void)in_sizes; (void)n_in; (void)out_size; (void)ws_size;
  const float* x   = (const float*)d_in[0];
  const float* wqw = (const float*)d_in[1];
  const float* wqb = (const float*)d_in[2];
  const float* wkw = (const float*)d_in[3];
  const float* wkb = (const float*)d_in[4];
  const float* wvw = (const float*)d_in[5];
  const float* wvb = (const float*)d_in[6];
  const float* wow = (const float*)d_in[7];
  const float* wob = (const float*)d_in[8];

  char* ws = (char*)d_ws;
  short* xb   = (short*)(ws + 0);           // 12,582,912 B (x bf16; later reused as attn out)
  short* wqkv = (short*)(ws + 12582912);    //  3,538,944
  short* wo16 = (short*)(ws + 16121856);    //  1,179,648
  float* bqkv = (float*)(ws + 17301504);    //      9,216
  short* qb   = (short*)(ws + 17310720);    // 12,582,912 (Q, pre-scaled)
  short* kb   = (short*)(ws + 29893632);    // 12,582,912
  short* vb   = (short*)(ws + 42476544);    // 12,582,912 V^T [b,h,d,s] (end 55,059,456)

  prep_x_kern<<<dim3(6144), dim3(256), 0, stream>>>(x, xb);
  prep_w_kern<<<dim3(2313), dim3(256), 0, stream>>>(wqw, wkw, wvw, wow, wqb, wkb, wvb,
                                                    wqkv, wo16, bqkv);
  gemm128<0><<<dim3(QKVN / 128, TOK / 128), dim3(256), 0, stream>>>(
      xb, wqkv, bqkv, qb, kb, vb, nullptr, TOK, QKVN, NEMBD);
  attn_kern<<<dim3(SEQ / 64, 48), dim3(256), 0, stream>>>(qb, kb, vb, xb);
  gemm128<1><<<dim3(NEMBD / 128, TOK / 128), dim3(256), 0, stream>>>(
      xb, wo16, wob, nullptr, nullptr, nullptr, (float*)d_out, TOK, NEMBD, NEMBD);
}

// Round 3
// 199.505 us; speedup vs baseline: 1.2273x; 1.0135x over previous
//
#include <hip/hip_runtime.h>
#include <stdint.h>
#include <stddef.h>

#define NEMBD 768
#define NH    12
#define HD    64
#define SEQ   2048
#define TOK   8192
#define QKVN  2304
#define NT    (SEQ / 64)
#define QSCALE 0.18033688011112042f   // log2(e)/8

typedef __attribute__((ext_vector_type(4))) float f32x4;
typedef __attribute__((ext_vector_type(8))) __bf16 bf8;
typedef __attribute__((ext_vector_type(8))) short s16x8;
typedef __attribute__((ext_vector_type(4))) short s16x4;

static __device__ __forceinline__ short f2bf(float f) {
  __bf16 h = (__bf16)f;
  union { __bf16 h; short s; } u; u.h = h; return u.s;
}

typedef const __attribute__((address_space(1))) unsigned int* gp1;
typedef __attribute__((address_space(3))) unsigned int* lp3;
static __device__ __forceinline__ void gload_lds16(const void* g, void* l) {
  __builtin_amdgcn_global_load_lds((gp1)g, (lp3)l, 16, 0, 0);
}

// ---------------- prep: fp32 -> bf16 conversions ----------------
__global__ __launch_bounds__(256) void prep_x_kern(const float* __restrict__ x,
                                                   short* __restrict__ xb) {
  int i = (blockIdx.x * 256 + threadIdx.x) * 4;
  f32x4 v = *(const f32x4*)(x + i);
  s16x4 o;
#pragma unroll
  for (int j = 0; j < 4; ++j) o[j] = f2bf(v[j]);
  *(s16x4*)(xb + i) = o;
}

__global__ __launch_bounds__(256) void prep_w_kern(
    const float* __restrict__ wq, const float* __restrict__ wk, const float* __restrict__ wv,
    const float* __restrict__ wo, const float* __restrict__ bq, const float* __restrict__ bk,
    const float* __restrict__ bv, short* __restrict__ wqkv, short* __restrict__ wo16,
    float* __restrict__ bqkv) {
  const int WN = NEMBD * NEMBD;
  int t = blockIdx.x * 256 + threadIdx.x;
  const int n4 = WN;
  if (t < n4) {
    int i4 = t * 4;
    const float* src; short* dst; int rem;
    if (i4 < 3 * WN) {
      int which = i4 / WN;
      rem = i4 - which * WN;
      src = which == 0 ? wq : (which == 1 ? wk : wv);
      dst = wqkv + i4;
    } else {
      rem = i4 - 3 * WN;
      src = wo;
      dst = wo16 + rem;
    }
    f32x4 v = *(const f32x4*)(src + rem);
    s16x4 o;
#pragma unroll
    for (int j = 0; j < 4; ++j) o[j] = f2bf(v[j]);
    *(s16x4*)dst = o;
  } else {
    int t2 = t - n4;
    if (t2 < QKVN) {
      int which = t2 / NEMBD, rem = t2 - which * NEMBD;
      bqkv[t2] = (which == 0 ? bq : (which == 1 ? bk : bv))[rem];
    }
  }
}

// ---------------- GEMM: C[m][n] = sum_k A[m][k]*B[n][k] + bias[n] ----------------
template <int MODE>
__global__ __launch_bounds__(256) void gemm128(
    const short* __restrict__ A, const short* __restrict__ Bw, const float* __restrict__ bias,
    short* __restrict__ q_out, short* __restrict__ k_out, short* __restrict__ v_out,
    float* __restrict__ c_out, int M, int N, int K) {
  __shared__ short As[128 * 64];
  __shared__ short Bs[128 * 64];
  const int tid = threadIdx.x;
  const int wave = tid >> 6, lane = tid & 63;
  const int r = lane & 15, g = lane >> 4;
  const int n0 = blockIdx.x * 128, m0 = blockIdx.y * 128;
  const int wm0 = (wave >> 1) * 64, wn0 = (wave & 1) * 64;
  const int lrow = lane >> 3, lcol = (lane & 7) * 8;

  f32x4 acc[4][4];
#pragma unroll
  for (int mi = 0; mi < 4; ++mi)
#pragma unroll
    for (int ni = 0; ni < 4; ++ni) acc[mi][ni] = (f32x4){0.f, 0.f, 0.f, 0.f};

  for (int kt = 0; kt < K; kt += 64) {
#pragma unroll
    for (int ii = 0; ii < 4; ++ii) {
      int blk = wave * 4 + ii;
      gload_lds16(A + (size_t)(m0 + blk * 8 + lrow) * K + kt + lcol, &As[blk * 512]);
      gload_lds16(Bw + (size_t)(n0 + blk * 8 + lrow) * K + kt + lcol, &Bs[blk * 512]);
    }
    __syncthreads();
#pragma unroll
    for (int kk = 0; kk < 2; ++kk) {
      bf8 af[4], bfv[4];
#pragma unroll
      for (int mi = 0; mi < 4; ++mi)
        af[mi] = *(const bf8*)&As[(wm0 + 16 * mi + r) * 64 + kk * 32 + g * 8];
#pragma unroll
      for (int ni = 0; ni < 4; ++ni)
        bfv[ni] = *(const bf8*)&Bs[(wn0 + 16 * ni + r) * 64 + kk * 32 + g * 8];
#pragma unroll
      for (int mi = 0; mi < 4; ++mi)
#pragma unroll
        for (int ni = 0; ni < 4; ++ni)
          acc[mi][ni] = __builtin_amdgcn_mfma_f32_16x16x32_bf16(af[mi], bfv[ni], acc[mi][ni], 0, 0, 0);
    }
    __syncthreads();
  }

#pragma unroll
  for (int ni = 0; ni < 4; ++ni) {
    int col = n0 + wn0 + 16 * ni + r;
    float bcol = bias[col];
    if (MODE == 0) {
      int which = col / NEMBD;
      int rem = col - which * NEMBD;
      int h = rem >> 6, d = rem & 63;
      if (which == 2) {
#pragma unroll
        for (int mi = 0; mi < 4; ++mi) {
          int s0 = m0 + wm0 + 16 * mi + 4 * g;
          int b = s0 >> 11, s = s0 & 2047;
          s16x4 pk;
#pragma unroll
          for (int j = 0; j < 4; ++j) pk[j] = f2bf(acc[mi][ni][j] + bcol);
          *(s16x4*)&v_out[(((size_t)(b * NH + h)) * HD + d) * SEQ + s] = pk;
        }
      } else {
        short* dst = which == 0 ? q_out : k_out;
        float sc = which == 0 ? QSCALE : 1.0f;
#pragma unroll
        for (int mi = 0; mi < 4; ++mi)
#pragma unroll
          for (int j = 0; j < 4; ++j) {
            int row = m0 + wm0 + 16 * mi + 4 * g + j;
            int b = row >> 11, s = row & 2047;
            dst[(((size_t)(b * NH + h)) * SEQ + s) * HD + d] = f2bf((acc[mi][ni][j] + bcol) * sc);
          }
      }
    } else {
#pragma unroll
      for (int mi = 0; mi < 4; ++mi)
#pragma unroll
        for (int j = 0; j < 4; ++j) {
          int row = m0 + wm0 + 16 * mi + 4 * g + j;
          c_out[(size_t)row * N + col] = acc[mi][ni][j] + bcol;
        }
    }
  }
}

// ---------------- flash attention (double-buffered, prefetch depth 1) ----------------
__global__ __launch_bounds__(256) void attn_kern(
    const short* __restrict__ Qg, const short* __restrict__ Kg, const short* __restrict__ Vtg,
    short* __restrict__ Ao) {
  __shared__ short Kl[2][64 * 64];       // swizzled [c][d]
  __shared__ short Vl[2][64 * 64];       // swizzled [d][c]
  __shared__ short Pl[4][16 * 64];       // per-wave P[r][c], XOR-swizzled

  const int tid = threadIdx.x;
  const int wave = tid >> 6, lane = tid & 63;
  const int r = lane & 15, g = lane >> 4;
  const int bh = blockIdx.y;
  const int q0 = blockIdx.x * 64;
  const size_t base = (size_t)bh * (SEQ * HD);

  bf8 qf[2];
#pragma unroll
  for (int kk = 0; kk < 2; ++kk)
    qf[kk] = *(const bf8*)&Qg[base + (size_t)(q0 + wave * 16 + r) * HD + kk * 32 + g * 8];

  float m_run = -__builtin_inff(), lsum = 0.f;
  f32x4 o[4];
#pragma unroll
  for (int fd = 0; fd < 4; ++fd) o[fd] = (f32x4){0.f, 0.f, 0.f, 0.f};

  const int cbr = (r & 7) << 4;          // read-side XOR (bytes)
  short* Pw = &Pl[wave][0];

  // staging geometry (per thread)
  const int srow = tid >> 3;
  const int sc8 = ((tid & 7) ^ (srow & 7)) * 8;
  const int srow2 = (256 + tid) >> 3;
  const int sc82 = (((256 + tid) & 7) ^ (srow2 & 7)) * 8;

#define ATTN_STAGE(T, KBUF, VBUF)                                                      \
  {                                                                                    \
    gload_lds16(Kg + base + (size_t)((T) * 64 + srow) * HD + sc8, (KBUF) + wave * 512);\
    gload_lds16(Vtg + base + (size_t)srow * SEQ + (T) * 64 + sc8, (VBUF) + wave * 512);\
    gload_lds16(Kg + base + (size_t)((T) * 64 + srow2) * HD + sc82,                    \
                (KBUF) + 2048 + wave * 512);                                           \
    gload_lds16(Vtg + base + (size_t)srow2 * SEQ + (T) * 64 + sc82,                    \
                (VBUF) + 2048 + wave * 512);                                           \
  }

#define ATTN_TILE(KBUF, VBUF)                                                          \
  {                                                                                    \
    f32x4 sv[4];                                                                       \
    _Pragma("unroll") for (int f = 0; f < 4; ++f) sv[f] = (f32x4){0.f, 0.f, 0.f, 0.f}; \
    __builtin_amdgcn_s_setprio(1);                                                     \
    _Pragma("unroll") for (int kk = 0; kk < 2; ++kk) {                                 \
      int cb = (kk * 64 + g * 16) ^ cbr;                                               \
      _Pragma("unroll") for (int f = 0; f < 4; ++f) {                                  \
        bf8 kf = *(const bf8*)((const char*)(KBUF) + (16 * f + r) * 128 + cb);         \
        sv[f] = __builtin_amdgcn_mfma_f32_16x16x32_bf16(kf, qf[kk], sv[f], 0, 0, 0);   \
      }                                                                                \
    }                                                                                  \
    __builtin_amdgcn_s_setprio(0);                                                     \
    float pf[16];                                                                      \
    _Pragma("unroll") for (int f = 0; f < 4; ++f)                                      \
      _Pragma("unroll") for (int j = 0; j < 4; ++j) pf[4 * f + j] = sv[f][j];          \
    float x0 = fmaxf(pf[0], pf[1]), x1 = fmaxf(pf[2], pf[3]);                          \
    float x2 = fmaxf(pf[4], pf[5]), x3 = fmaxf(pf[6], pf[7]);                          \
    float x4 = fmaxf(pf[8], pf[9]), x5 = fmaxf(pf[10], pf[11]);                        \
    float x6 = fmaxf(pf[12], pf[13]), x7 = fmaxf(pf[14], pf[15]);                      \
    float y0 = fmaxf(x0, x1), y1 = fmaxf(x2, x3), y2 = fmaxf(x4, x5),                  \
          y3 = fmaxf(x6, x7);                                                          \
    float tmax = fmaxf(fmaxf(y0, y1), fmaxf(y2, y3));                                  \
    tmax = fmaxf(tmax, __shfl_xor(tmax, 16));                                          \
    tmax = fmaxf(tmax, __shfl_xor(tmax, 32));                                          \
    float m_new = fmaxf(m_run, tmax);                                                  \
    float corr = __builtin_amdgcn_exp2f(m_run - m_new);                                \
    _Pragma("unroll") for (int i = 0; i < 16; ++i)                                     \
      pf[i] = __builtin_amdgcn_exp2f(pf[i] - m_new);                                   \
    float a0 = pf[0] + pf[1], a1 = pf[2] + pf[3], a2 = pf[4] + pf[5],                  \
          a3 = pf[6] + pf[7];                                                          \
    float a4 = pf[8] + pf[9], a5 = pf[10] + pf[11], a6 = pf[12] + pf[13],              \
          a7 = pf[14] + pf[15];                                                        \
    float b0 = a0 + a1, b1 = a2 + a3, b2 = a4 + a5, b3 = a6 + a7;                      \
    float tsum = (b0 + b1) + (b2 + b3);                                                \
    tsum += __shfl_xor(tsum, 16);                                                      \
    tsum += __shfl_xor(tsum, 32);                                                      \
    lsum = lsum * corr + tsum;                                                         \
    _Pragma("unroll") for (int f = 0; f < 4; ++f) {                                    \
      s16x4 pk;                                                                        \
      _Pragma("unroll") for (int j = 0; j < 4; ++j) pk[j] = f2bf(pf[4 * f + j]);       \
      *(s16x4*)((char*)Pw + r * 128 + ((32 * f + 8 * g) ^ cbr)) = pk;                  \
    }                                                                                  \
    if (!__all(m_new == m_run)) {                                                      \
      _Pragma("unroll") for (int j = 0; j < 4; ++j) {                                  \
        float cj = __shfl(corr, 4 * g + j);                                            \
        _Pragma("unroll") for (int fd = 0; fd < 4; ++fd) o[fd][j] *= cj;               \
      }                                                                                \
    }                                                                                  \
    m_run = m_new;                                                                     \
    __builtin_amdgcn_s_setprio(1);                                                     \
    _Pragma("unroll") for (int kk = 0; kk < 2; ++kk) {                                 \
      bf8 pa = *(const bf8*)((const char*)Pw + r * 128 + ((64 * kk + 16 * g) ^ cbr));  \
      int cb = (kk * 64 + g * 16) ^ cbr;                                               \
      _Pragma("unroll") for (int fd = 0; fd < 4; ++fd) {                               \
        bf8 vb = *(const bf8*)((const char*)(VBUF) + (16 * fd + r) * 128 + cb);        \
        o[fd] = __builtin_amdgcn_mfma_f32_16x16x32_bf16(pa, vb, o[fd], 0, 0, 0);       \
      }                                                                                \
    }                                                                                  \
    __builtin_amdgcn_s_setprio(0);                                                     \
  }

  ATTN_STAGE(0, &Kl[0][0], &Vl[0][0]);
  for (int tt = 0; tt < NT; tt += 2) {
    __syncthreads();
    ATTN_STAGE(tt + 1, &Kl[1][0], &Vl[1][0]);
    ATTN_TILE(&Kl[0][0], &Vl[0][0]);
    __syncthreads();
    if (tt + 2 < NT) ATTN_STAGE(tt + 2, &Kl[0][0], &Vl[0][0]);
    ATTN_TILE(&Kl[1][0], &Vl[1][0]);
  }

  float inv = 1.f / lsum;
  const int b = bh / NH, h = bh - b * NH;
#pragma unroll
  for (int j = 0; j < 4; ++j) {
    float ij = __shfl(inv, 4 * g + j);
    int srow_o = q0 + wave * 16 + 4 * g + j;
    size_t obase = ((size_t)(b * SEQ + srow_o)) * NEMBD + h * HD;
#pragma unroll
    for (int fd = 0; fd < 4; ++fd)
      Ao[obase + 16 * fd + r] = f2bf(o[fd][j] * ij);
  }
}

// ---------------- launcher ----------------
extern "C" void kernel_launch(void* const* d_in, const int* in_sizes, int n_in,
                              void* d_out, int out_size, void* d_ws, size_t ws_size,
                              hipStream_t stream) {
  (void)in_sizes; (void)n_in; (void)out_size; (void)ws_size;
  const float* x   = (const float*)d_in[0];
  const float* wqw = (const float*)d_in[1];
  const float* wqb = (const float*)d_in[2];
  const float* wkw = (const float*)d_in[3];
  const float* wkb = (const float*)d_in[4];
  const float* wvw = (const float*)d_in[5];
  const float* wvb = (const float*)d_in[6];
  const float* wow = (const float*)d_in[7];
  const float* wob = (const float*)d_in[8];

  char* ws = (char*)d_ws;
  short* xb   = (short*)(ws + 0);           // x bf16; later reused as attn out
  short* wqkv = (short*)(ws + 12582912);
  short* wo16 = (short*)(ws + 16121856);
  float* bqkv = (float*)(ws + 17301504);
  short* qb   = (short*)(ws + 17310720);    // Q, pre-scaled by log2(e)/8
  short* kb   = (short*)(ws + 29893632);
  short* vb   = (short*)(ws + 42476544);    // V^T [b,h,d,s]

  prep_x_kern<<<dim3(6144), dim3(256), 0, stream>>>(x, xb);
  prep_w_kern<<<dim3(2313), dim3(256), 0, stream>>>(wqw, wkw, wvw, wow, wqb, wkb, wvb,
                                                    wqkv, wo16, bqkv);
  gemm128<0><<<dim3(QKVN / 128, TOK / 128), dim3(256), 0, stream>>>(
      xb, wqkv, bqkv, qb, kb, vb, nullptr, TOK, QKVN, NEMBD);
  attn_kern<<<dim3(SEQ / 64, 48), dim3(256), 0, stream>>>(qb, kb, vb, xb);
  gemm128<1><<<dim3(NEMBD / 128, TOK / 128), dim3(256), 0, stream>>>(
      xb, wo16, wob, nullptr, nullptr, nullptr, (float*)d_out, TOK, NEMBD, NEMBD);
}

// Round 4
// 188.943 us; speedup vs baseline: 1.2959x; 1.0559x over previous
//
#include <hip/hip_runtime.h>
#include <stdint.h>
#include <stddef.h>

#define NEMBD 768
#define NH    12
#define HD    64
#define SEQ   2048
#define TOK   8192
#define QKVN  2304
#define NT    (SEQ / 64)
#define QSCALE 0.18033688011112042f   // log2(e)/8

typedef __attribute__((ext_vector_type(4))) float f32x4;
typedef __attribute__((ext_vector_type(8))) __bf16 bf8;
typedef __attribute__((ext_vector_type(8))) short s16x8;
typedef __attribute__((ext_vector_type(4))) short s16x4;

static __device__ __forceinline__ short f2bf(float f) {
  __bf16 h = (__bf16)f;
  union { __bf16 h; short s; } u; u.h = h; return u.s;
}

typedef const __attribute__((address_space(1))) unsigned int* gp1;
typedef __attribute__((address_space(3))) unsigned int* lp3;
static __device__ __forceinline__ void gload_lds16(const void* g, void* l) {
  __builtin_amdgcn_global_load_lds((gp1)g, (lp3)l, 16, 0, 0);
}

// ---------------- prep: fp32 -> bf16 conversions ----------------
__global__ __launch_bounds__(256) void prep_x_kern(const float* __restrict__ x,
                                                   short* __restrict__ xb) {
  int i = (blockIdx.x * 256 + threadIdx.x) * 4;
  f32x4 v = *(const f32x4*)(x + i);
  s16x4 o;
#pragma unroll
  for (int j = 0; j < 4; ++j) o[j] = f2bf(v[j]);
  *(s16x4*)(xb + i) = o;
}

__global__ __launch_bounds__(256) void prep_w_kern(
    const float* __restrict__ wq, const float* __restrict__ wk, const float* __restrict__ wv,
    const float* __restrict__ wo, const float* __restrict__ bq, const float* __restrict__ bk,
    const float* __restrict__ bv, short* __restrict__ wqkv, short* __restrict__ wo16,
    float* __restrict__ bqkv) {
  const int WN = NEMBD * NEMBD;
  int t = blockIdx.x * 256 + threadIdx.x;
  const int n4 = WN;
  if (t < n4) {
    int i4 = t * 4;
    const float* src; short* dst; int rem;
    if (i4 < 3 * WN) {
      int which = i4 / WN;
      rem = i4 - which * WN;
      src = which == 0 ? wq : (which == 1 ? wk : wv);
      dst = wqkv + i4;
    } else {
      rem = i4 - 3 * WN;
      src = wo;
      dst = wo16 + rem;
    }
    f32x4 v = *(const f32x4*)(src + rem);
    s16x4 o;
#pragma unroll
    for (int j = 0; j < 4; ++j) o[j] = f2bf(v[j]);
    *(s16x4*)dst = o;
  } else {
    int t2 = t - n4;
    if (t2 < QKVN) {
      int which = t2 / NEMBD, rem = t2 - which * NEMBD;
      bqkv[t2] = (which == 0 ? bq : (which == 1 ? bk : bv))[rem];
    }
  }
}

// ---------------- GEMM: C[m][n] = sum_k A[m][k]*B[n][k] + bias[n] ----------------
template <int MODE>
__global__ __launch_bounds__(256) void gemm128(
    const short* __restrict__ A, const short* __restrict__ Bw, const float* __restrict__ bias,
    short* __restrict__ q_out, short* __restrict__ k_out, short* __restrict__ v_out,
    float* __restrict__ c_out, int M, int N, int K) {
  __shared__ short As[128 * 64];
  __shared__ short Bs[128 * 64];
  const int tid = threadIdx.x;
  const int wave = tid >> 6, lane = tid & 63;
  const int r = lane & 15, g = lane >> 4;
  const int n0 = blockIdx.x * 128, m0 = blockIdx.y * 128;
  const int wm0 = (wave >> 1) * 64, wn0 = (wave & 1) * 64;
  const int lrow = lane >> 3, lcol = (lane & 7) * 8;

  f32x4 acc[4][4];
#pragma unroll
  for (int mi = 0; mi < 4; ++mi)
#pragma unroll
    for (int ni = 0; ni < 4; ++ni) acc[mi][ni] = (f32x4){0.f, 0.f, 0.f, 0.f};

  for (int kt = 0; kt < K; kt += 64) {
#pragma unroll
    for (int ii = 0; ii < 4; ++ii) {
      int blk = wave * 4 + ii;
      gload_lds16(A + (size_t)(m0 + blk * 8 + lrow) * K + kt + lcol, &As[blk * 512]);
      gload_lds16(Bw + (size_t)(n0 + blk * 8 + lrow) * K + kt + lcol, &Bs[blk * 512]);
    }
    __syncthreads();
#pragma unroll
    for (int kk = 0; kk < 2; ++kk) {
      bf8 af[4], bfv[4];
#pragma unroll
      for (int mi = 0; mi < 4; ++mi)
        af[mi] = *(const bf8*)&As[(wm0 + 16 * mi + r) * 64 + kk * 32 + g * 8];
#pragma unroll
      for (int ni = 0; ni < 4; ++ni)
        bfv[ni] = *(const bf8*)&Bs[(wn0 + 16 * ni + r) * 64 + kk * 32 + g * 8];
#pragma unroll
      for (int mi = 0; mi < 4; ++mi)
#pragma unroll
        for (int ni = 0; ni < 4; ++ni)
          acc[mi][ni] = __builtin_amdgcn_mfma_f32_16x16x32_bf16(af[mi], bfv[ni], acc[mi][ni], 0, 0, 0);
    }
    __syncthreads();
  }

#pragma unroll
  for (int ni = 0; ni < 4; ++ni) {
    int col = n0 + wn0 + 16 * ni + r;
    float bcol = bias[col];
    if (MODE == 0) {
      int which = col / NEMBD;
      int rem = col - which * NEMBD;
      int h = rem >> 6, d = rem & 63;
      if (which == 2) {
#pragma unroll
        for (int mi = 0; mi < 4; ++mi) {
          int s0 = m0 + wm0 + 16 * mi + 4 * g;
          int b = s0 >> 11, s = s0 & 2047;
          s16x4 pk;
#pragma unroll
          for (int j = 0; j < 4; ++j) pk[j] = f2bf(acc[mi][ni][j] + bcol);
          *(s16x4*)&v_out[(((size_t)(b * NH + h)) * HD + d) * SEQ + s] = pk;
        }
      } else {
        short* dst = which == 0 ? q_out : k_out;
        float sc = which == 0 ? QSCALE : 1.0f;
#pragma unroll
        for (int mi = 0; mi < 4; ++mi)
#pragma unroll
          for (int j = 0; j < 4; ++j) {
            int row = m0 + wm0 + 16 * mi + 4 * g + j;
            int b = row >> 11, s = row & 2047;
            dst[(((size_t)(b * NH + h)) * SEQ + s) * HD + d] = f2bf((acc[mi][ni][j] + bcol) * sc);
          }
      }
    } else {
#pragma unroll
      for (int mi = 0; mi < 4; ++mi)
#pragma unroll
        for (int j = 0; j < 4; ++j) {
          int row = m0 + wm0 + 16 * mi + 4 * g + j;
          c_out[(size_t)row * N + col] = acc[mi][ni][j] + bcol;
        }
    }
  }
}

// ---------------- flash attention ----------------
// VALU-minimized softmax: row-sum via MFMA (ones B-operand), lsum j-keyed
// (rescaled with O), threshold-deferred max updates, max3 trees.
__global__ __launch_bounds__(256) void attn_kern(
    const short* __restrict__ Qg, const short* __restrict__ Kg, const short* __restrict__ Vtg,
    short* __restrict__ Ao) {
  __shared__ short Kl[2][64 * 64];       // swizzled [c][d]
  __shared__ short Vl[2][64 * 64];       // swizzled [d][c]
  __shared__ short Pl[4][16 * 64];       // per-wave P[r][c], XOR-swizzled

  const int tid = threadIdx.x;
  const int wave = tid >> 6, lane = tid & 63;
  const int r = lane & 15, g = lane >> 4;
  const int bh = blockIdx.y;
  const int q0 = blockIdx.x * 64;
  const size_t base = (size_t)bh * (SEQ * HD);

  bf8 qf[2];
#pragma unroll
  for (int kk = 0; kk < 2; ++kk)
    qf[kk] = *(const bf8*)&Qg[base + (size_t)(q0 + wave * 16 + r) * HD + kk * 32 + g * 8];

  // bf16 1.0 vector for the MFMA row-sum
  union { short s; __bf16 h; } one_u; one_u.s = 0x3F80;
  bf8 vones;
#pragma unroll
  for (int i = 0; i < 8; ++i) vones[i] = one_u.h;

  float m_run = -__builtin_inff();
  f32x4 o[4], osum;
#pragma unroll
  for (int fd = 0; fd < 4; ++fd) o[fd] = (f32x4){0.f, 0.f, 0.f, 0.f};
  osum = (f32x4){0.f, 0.f, 0.f, 0.f};

  const int cbr = (r & 7) << 4;          // read-side XOR (bytes)
  short* Pw = &Pl[wave][0];

  const int srow = tid >> 3;
  const int sc8 = ((tid & 7) ^ (srow & 7)) * 8;
  const int srow2 = (256 + tid) >> 3;
  const int sc82 = (((256 + tid) & 7) ^ (srow2 & 7)) * 8;

#define ATTN_STAGE(T, KBUF, VBUF)                                                      \
  {                                                                                    \
    gload_lds16(Kg + base + (size_t)((T) * 64 + srow) * HD + sc8, (KBUF) + wave * 512);\
    gload_lds16(Vtg + base + (size_t)srow * SEQ + (T) * 64 + sc8, (VBUF) + wave * 512);\
    gload_lds16(Kg + base + (size_t)((T) * 64 + srow2) * HD + sc82,                    \
                (KBUF) + 2048 + wave * 512);                                           \
    gload_lds16(Vtg + base + (size_t)srow2 * SEQ + (T) * 64 + sc82,                    \
                (VBUF) + 2048 + wave * 512);                                           \
  }

#define ATTN_TILE(KBUF, VBUF)                                                          \
  {                                                                                    \
    f32x4 sv[4];                                                                       \
    _Pragma("unroll") for (int f = 0; f < 4; ++f) sv[f] = (f32x4){0.f, 0.f, 0.f, 0.f}; \
    __builtin_amdgcn_s_setprio(1);                                                     \
    _Pragma("unroll") for (int kk = 0; kk < 2; ++kk) {                                 \
      int cb = (kk * 64 + g * 16) ^ cbr;                                               \
      _Pragma("unroll") for (int f = 0; f < 4; ++f) {                                  \
        bf8 kf = *(const bf8*)((const char*)(KBUF) + (16 * f + r) * 128 + cb);         \
        sv[f] = __builtin_amdgcn_mfma_f32_16x16x32_bf16(kf, qf[kk], sv[f], 0, 0, 0);   \
      }                                                                                \
    }                                                                                  \
    __builtin_amdgcn_s_setprio(0);                                                     \
    /* row max via max3-fused triples */                                               \
    float c0 = fmaxf(fmaxf(sv[0][0], sv[0][1]), sv[0][2]);                             \
    float c1 = fmaxf(fmaxf(sv[0][3], sv[1][0]), sv[1][1]);                             \
    float c2 = fmaxf(fmaxf(sv[1][2], sv[1][3]), sv[2][0]);                             \
    float c3 = fmaxf(fmaxf(sv[2][1], sv[2][2]), sv[2][3]);                             \
    float c4 = fmaxf(fmaxf(sv[3][0], sv[3][1]), sv[3][2]);                             \
    float d0 = fmaxf(fmaxf(c0, c1), c2);                                               \
    float d1 = fmaxf(fmaxf(c3, c4), sv[3][3]);                                         \
    float tmax = fmaxf(d0, d1);                                                        \
    tmax = fmaxf(tmax, __shfl_xor(tmax, 16));                                          \
    tmax = fmaxf(tmax, __shfl_xor(tmax, 32));                                          \
    if (__any(tmax > m_run + 8.0f)) {                                                  \
      float m_new = fmaxf(m_run, tmax);                                                \
      float corr = __builtin_amdgcn_exp2f(m_run - m_new);                              \
      _Pragma("unroll") for (int j = 0; j < 4; ++j) {                                  \
        float cj = __shfl(corr, 4 * g + j);                                            \
        _Pragma("unroll") for (int fd = 0; fd < 4; ++fd) o[fd][j] *= cj;               \
        osum[j] *= cj;                                                                 \
      }                                                                                \
      m_run = m_new;                                                                   \
    }                                                                                  \
    _Pragma("unroll") for (int f = 0; f < 4; ++f) {                                    \
      s16x4 pk;                                                                        \
      _Pragma("unroll") for (int j = 0; j < 4; ++j)                                    \
        pk[j] = f2bf(__builtin_amdgcn_exp2f(sv[f][j] - m_run));                        \
      *(s16x4*)((char*)Pw + r * 128 + ((32 * f + 8 * g) ^ cbr)) = pk;                  \
    }                                                                                  \
    __builtin_amdgcn_s_setprio(1);                                                     \
    _Pragma("unroll") for (int kk = 0; kk < 2; ++kk) {                                 \
      bf8 pa = *(const bf8*)((const char*)Pw + r * 128 + ((64 * kk + 16 * g) ^ cbr));  \
      int cb = (kk * 64 + g * 16) ^ cbr;                                               \
      osum = __builtin_amdgcn_mfma_f32_16x16x32_bf16(pa, vones, osum, 0, 0, 0);        \
      _Pragma("unroll") for (int fd = 0; fd < 4; ++fd) {                               \
        bf8 vb = *(const bf8*)((const char*)(VBUF) + (16 * fd + r) * 128 + cb);        \
        o[fd] = __builtin_amdgcn_mfma_f32_16x16x32_bf16(pa, vb, o[fd], 0, 0, 0);       \
      }                                                                                \
    }                                                                                  \
    __builtin_amdgcn_s_setprio(0);                                                     \
  }

  ATTN_STAGE(0, &Kl[0][0], &Vl[0][0]);
  for (int tt = 0; tt < NT; tt += 2) {
    __syncthreads();
    ATTN_STAGE(tt + 1, &Kl[1][0], &Vl[1][0]);
    ATTN_TILE(&Kl[0][0], &Vl[0][0]);
    __syncthreads();
    if (tt + 2 < NT) ATTN_STAGE(tt + 2, &Kl[0][0], &Vl[0][0]);
    ATTN_TILE(&Kl[1][0], &Vl[1][0]);
  }

  const int b = bh / NH, h = bh - b * NH;
#pragma unroll
  for (int j = 0; j < 4; ++j) {
    float ij = 1.f / osum[j];
    int srow_o = q0 + wave * 16 + 4 * g + j;
    size_t obase = ((size_t)(b * SEQ + srow_o)) * NEMBD + h * HD;
#pragma unroll
    for (int fd = 0; fd < 4; ++fd)
      Ao[obase + 16 * fd + r] = f2bf(o[fd][j] * ij);
  }
}

// ---------------- launcher ----------------
extern "C" void kernel_launch(void* const* d_in, const int* in_sizes, int n_in,
                              void* d_out, int out_size, void* d_ws, size_t ws_size,
                              hipStream_t stream) {
  (void)in_sizes; (void)n_in; (void)out_size; (void)ws_size;
  const float* x   = (const float*)d_in[0];
  const float* wqw = (const float*)d_in[1];
  const float* wqb = (const float*)d_in[2];
  const float* wkw = (const float*)d_in[3];
  const float* wkb = (const float*)d_in[4];
  const float* wvw = (const float*)d_in[5];
  const float* wvb = (const float*)d_in[6];
  const float* wow = (const float*)d_in[7];
  const float* wob = (const float*)d_in[8];

  char* ws = (char*)d_ws;
  short* xb   = (short*)(ws + 0);           // x bf16; later reused as attn out
  short* wqkv = (short*)(ws + 12582912);
  short* wo16 = (short*)(ws + 16121856);
  float* bqkv = (float*)(ws + 17301504);
  short* qb   = (short*)(ws + 17310720);    // Q, pre-scaled by log2(e)/8
  short* kb   = (short*)(ws + 29893632);
  short* vb   = (short*)(ws + 42476544);    // V^T [b,h,d,s]

  prep_x_kern<<<dim3(6144), dim3(256), 0, stream>>>(x, xb);
  prep_w_kern<<<dim3(2313), dim3(256), 0, stream>>>(wqw, wkw, wvw, wow, wqb, wkb, wvb,
                                                    wqkv, wo16, bqkv);
  gemm128<0><<<dim3(QKVN / 128, TOK / 128), dim3(256), 0, stream>>>(
      xb, wqkv, bqkv, qb, kb, vb, nullptr, TOK, QKVN, NEMBD);
  attn_kern<<<dim3(SEQ / 64, 48), dim3(256), 0, stream>>>(qb, kb, vb, xb);
  gemm128<1><<<dim3(NEMBD / 128, TOK / 128), dim3(256), 0, stream>>>(
      xb, wo16, wob, nullptr, nullptr, nullptr, (float*)d_out, TOK, NEMBD, NEMBD);
}